// Round 20
// baseline (434.361 us; speedup 1.0000x reference)
//
#include <hip/hip_runtime.h>
#include <hip/hip_bf16.h>

typedef __bf16 bf16;
typedef __attribute__((ext_vector_type(8))) __bf16 bf16x8;
typedef __attribute__((ext_vector_type(4))) float f32x4;

#define NB 2
#define NS 2048
#define ND 1024
#define NH 16
#define NHD 64
#define NFF 4096
#define NE 8
#define NT 4096

typedef const void __attribute__((address_space(1)))* gas_p;
typedef void __attribute__((address_space(3)))* las_p;

__device__ __forceinline__ void gload16(const bf16* g, char* l) {
  __builtin_amdgcn_global_load_lds((gas_p)g, (las_p)l, 16, 0, 0);
}

__device__ __forceinline__ float bf2f(bf16 v) { return (float)v; }

// ---------------------------------------------------------------------------
// Merged fp32->bf16 conversion for x (2048 blk), wqkv (1536), wo (512):
// one 4096-block dispatch; block 0 also zeroes the 32 meta ints.
// ---------------------------------------------------------------------------
__global__ void cvt3_kernel(const float* __restrict__ x, bf16* __restrict__ bx,
                            const float* __restrict__ wqkv, bf16* __restrict__ bwqkv,
                            const float* __restrict__ wo, bf16* __restrict__ bwo,
                            int* __restrict__ mz)
{
  const int b = blockIdx.x, tid = threadIdx.x;
  if (b == 0 && tid < 32) mz[tid] = 0;
  const float* src; bf16* dst; size_t off;
  if (b < 2048)      { src = x;    dst = bx;    off = (size_t)b * 2048; }
  else if (b < 3584) { src = wqkv; dst = bwqkv; off = (size_t)(b - 2048) * 2048; }
  else               { src = wo;   dst = bwo;   off = (size_t)(b - 3584) * 2048; }
  const size_t i = off + (size_t)tid * 8;
  float4 a = *(const float4*)(src + i);
  float4 c = *(const float4*)(src + i + 4);
  bf16x8 o;
  o[0] = (bf16)a.x; o[1] = (bf16)a.y; o[2] = (bf16)a.z; o[3] = (bf16)a.w;
  o[4] = (bf16)c.x; o[5] = (bf16)c.y; o[6] = (bf16)c.z; o[7] = (bf16)c.w;
  *(bf16x8*)(dst + i) = o;
}

// ---------------------------------------------------------------------------
// Dense 128x128 B^T GEMM, counted-vmcnt double-buffered (r16-proven):
// MODE 0: QKV proj -> scatter q/k/vT (+fp32 bias)
// MODE 1: out proj -> outf = acc + bias + residf (fp32)
// ---------------------------------------------------------------------------
template<int MODE>
__launch_bounds__(256, 2)
__global__ void gemm_bt(const bf16* __restrict__ A, const bf16* __restrict__ Bw,
                        const float* __restrict__ bias, const float* __restrict__ residf,
                        float* __restrict__ outf,
                        bf16* __restrict__ qws, bf16* __restrict__ kws, bf16* __restrict__ vtws,
                        int M, int N, int K)
{
  constexpr int STRIDE = 32768;
  __shared__ __align__(16) char smem[2 * STRIDE];
  const int tid = threadIdx.x;
  const int lane = tid & 63, w = tid >> 6;
  const int wr = w >> 1, wc = w & 1;
  const int l4 = lane >> 4, l15 = lane & 15;
  const int m0 = blockIdx.x * 128, n0 = blockIdx.y * 128;

  const bf16* arow[4];
  const bf16* brow[4];
  int aoff[4], boff[4];
#pragma unroll
  for (int it = 0; it < 4; ++it) {
    int chunk = it * 256 + tid;
    int row = chunk >> 3, p = chunk & 7;
    int xoff = (p ^ (row & 7)) * 8;
    aoff[it] = chunk * 16;
    boff[it] = 16384 + chunk * 16;
    arow[it] = A + (size_t)(m0 + row) * K + xoff;
    brow[it] = Bw + (size_t)(n0 + row) * K + xoff;
  }

  f32x4 acc[4][4];
  const f32x4 z4 = {0.f, 0.f, 0.f, 0.f};
#pragma unroll
  for (int i = 0; i < 4; ++i)
#pragma unroll
    for (int j = 0; j < 4; ++j) acc[i][j] = z4;

  const int NSTEP = K >> 6;
#pragma unroll
  for (int it = 0; it < 4; ++it) { gload16(arow[it], smem + aoff[it]);
                                   gload16(brow[it], smem + boff[it]); }
#pragma unroll
  for (int it = 0; it < 4; ++it) { gload16(arow[it] + 64, smem + STRIDE + aoff[it]);
                                   gload16(brow[it] + 64, smem + STRIDE + boff[it]); }
  asm volatile("s_waitcnt vmcnt(8)" ::: "memory");
  __builtin_amdgcn_sched_barrier(0);
  __builtin_amdgcn_s_barrier();

  int cur = 0;
  for (int st = 0; st < NSTEP; ++st) {
    const char* sA = smem + cur * STRIDE;
    const char* sB = sA + 16384;
#pragma unroll
    for (int ks = 0; ks < 2; ++ks) {
      bf16x8 af[4], bfr[4];
#pragma unroll
      for (int i = 0; i < 4; ++i) {
        int r = wr * 64 + i * 16 + l15;
        int ps = (ks * 4 + l4) ^ (r & 7);
        af[i] = *(const bf16x8*)(sA + r * 128 + ps * 16);
      }
#pragma unroll
      for (int j = 0; j < 4; ++j) {
        int r = wc * 64 + j * 16 + l15;
        int ps = (ks * 4 + l4) ^ (r & 7);
        bfr[j] = *(const bf16x8*)(sB + r * 128 + ps * 16);
      }
#pragma unroll
      for (int i = 0; i < 4; ++i)
#pragma unroll
        for (int j = 0; j < 4; ++j)
          acc[i][j] = __builtin_amdgcn_mfma_f32_16x16x32_bf16(af[i], bfr[j], acc[i][j], 0, 0, 0);
    }
    __builtin_amdgcn_s_barrier();
    if (st + 2 < NSTEP) {
      const int kt2 = (st + 2) << 6;
#pragma unroll
      for (int it = 0; it < 4; ++it) { gload16(arow[it] + kt2, smem + cur * STRIDE + aoff[it]);
                                       gload16(brow[it] + kt2, smem + cur * STRIDE + boff[it]); }
      asm volatile("s_waitcnt vmcnt(8)" ::: "memory");
    } else {
      asm volatile("s_waitcnt vmcnt(0)" ::: "memory");
    }
    __builtin_amdgcn_sched_barrier(0);
    __builtin_amdgcn_s_barrier();
    cur ^= 1;
  }

#pragma unroll
  for (int i = 0; i < 4; ++i) {
#pragma unroll
    for (int j = 0; j < 4; ++j) {
      int col = n0 + wc * 64 + j * 16 + l15;
      float bv = bias[col];
#pragma unroll
      for (int r = 0; r < 4; ++r) {
        int rl = wr * 64 + i * 16 + l4 * 4 + r;
        int grow = m0 + rl;
        float val = acc[i][j][r] + bv;
        if (MODE == 0) {
          int b = grow >> 11, s = grow & 2047;
          int which = col >> 10, d = col & 1023;
          int h = d >> 6, hd = d & 63;
          int bh = b * NH + h;
          if (which == 0)      qws[((size_t)(bh * NS + s)) * NHD + hd] = (bf16)val;
          else if (which == 1) kws[((size_t)(bh * NS + s)) * NHD + hd] = (bf16)val;
          else                 vtws[((size_t)(bh * NHD + hd)) * NS + s] = (bf16)val;
        } else {
          size_t o = (size_t)grow * ND + col;
          outf[o] = val + residf[o];
        }
      }
    }
  }
}

// ---------------------------------------------------------------------------
// Persistent MoE GEMM, counted-vmcnt double-buffered (r14/r17-proven, BM=64).
// MODE 2: GEMM1  outb[slot] = gelu(A[perm]@w1^T + b1)   (tanh GELU)
// MODE 3: GEMM2  outf[tok]  = A[slot]@w2^T + b2 + residb[tok]
// ---------------------------------------------------------------------------
template<int MODE, int BM, int MINW>
__launch_bounds__(256, MINW)
__global__ void gemm_moe(const bf16* __restrict__ A, const bf16* __restrict__ Bw,
                         const float* __restrict__ bias, const bf16* __restrict__ residb,
                         float* __restrict__ outf, bf16* __restrict__ outb,
                         const int* __restrict__ perm, const int* __restrict__ offs,
                         const int* __restrict__ tiles, int NTILN, int K)
{
  constexpr int BN = 128;
  constexpr int AI = BM / 32;
  constexpr int BI = 4;
  constexpr int STRIDE = (BM + BN) * 128;
  constexpr int WM = 2, WN = 2;
  constexpr int IM = BM / (16 * WM);
  constexpr int JN = BN / (16 * WN);
  __shared__ __align__(16) char smem[2 * STRIDE];
  const int tid = threadIdx.x;
  const int lane = tid & 63, w = tid >> 6;
  const int wr = w >> 1, wc = w & 1;
  const int l4 = lane >> 4, l15 = lane & 15;

  const int nmt = tiles[0];
  const int ntile = nmt * NTILN;
  const int q8 = ntile >> 3, r8 = ntile & 7;
  const int NSTEP = K >> 6;

  for (int u = blockIdx.x; u < ntile; u += gridDim.x) {
    const int xcd = u & 7, pos = u >> 3;
    const int t = (xcd < r8 ? xcd * (q8 + 1) : r8 * (q8 + 1) + (xcd - r8) * q8) + pos;

    const int mi = t % nmt, nj = t / nmt;
    const int pk = tiles[1 + mi];
    const int z = pk >> 16;
    const int m0 = (pk & 0xffff) * BM;
    const int n0 = nj * BN;
    const int slot0 = offs[z];
    const int ne = offs[z + 1] - slot0;
    const bf16* Bp = Bw + (size_t)z * ((MODE == 2) ? (NFF * ND) : (ND * NFF));
    const float* biasp = bias + z * ((MODE == 2) ? NFF : ND);

    const bf16* arow[AI];
    const bf16* brow[BI];
    int aoff[AI], boff[BI];
#pragma unroll
    for (int it = 0; it < AI; ++it) {
      int chunk = it * 256 + tid;
      int row = chunk >> 3, p = chunk & 7;
      int xoff = (p ^ (row & 7)) * 8;
      aoff[it] = chunk * 16;
      if (MODE == 2) {
        int tok = perm[slot0 + min(m0 + row, ne - 1)];
        arow[it] = A + (size_t)tok * K + xoff;
      } else {
        int r2 = min(m0 + row, ne - 1);
        arow[it] = A + (size_t)(slot0 + r2) * K + xoff;
      }
    }
#pragma unroll
    for (int it = 0; it < BI; ++it) {
      int chunk = it * 256 + tid;
      int row = chunk >> 3, p = chunk & 7;
      int xoff = (p ^ (row & 7)) * 8;
      boff[it] = BM * 128 + chunk * 16;
      brow[it] = Bp + (size_t)(n0 + row) * K + xoff;
    }

    f32x4 acc[IM][JN];
    const f32x4 z4 = {0.f, 0.f, 0.f, 0.f};
#pragma unroll
    for (int i = 0; i < IM; ++i)
#pragma unroll
      for (int j = 0; j < JN; ++j) acc[i][j] = z4;

#pragma unroll
    for (int it = 0; it < AI; ++it) gload16(arow[it], smem + aoff[it]);
#pragma unroll
    for (int it = 0; it < BI; ++it) gload16(brow[it], smem + boff[it]);
#pragma unroll
    for (int it = 0; it < AI; ++it) gload16(arow[it] + 64, smem + STRIDE + aoff[it]);
#pragma unroll
    for (int it = 0; it < BI; ++it) gload16(brow[it] + 64, smem + STRIDE + boff[it]);
    asm volatile("s_waitcnt vmcnt(6)" ::: "memory");
    __builtin_amdgcn_sched_barrier(0);
    __builtin_amdgcn_s_barrier();

    int cur = 0;
    for (int st = 0; st < NSTEP; ++st) {
      const char* sA = smem + cur * STRIDE;
      const char* sB = sA + BM * 128;
#pragma unroll
      for (int ks = 0; ks < 2; ++ks) {
        bf16x8 af[IM], bfr[JN];
#pragma unroll
        for (int i = 0; i < IM; ++i) {
          int r = wr * 16 * IM + i * 16 + l15;
          int ps = (ks * 4 + l4) ^ (r & 7);
          af[i] = *(const bf16x8*)(sA + r * 128 + ps * 16);
        }
#pragma unroll
        for (int j = 0; j < JN; ++j) {
          int r = wc * 16 * JN + j * 16 + l15;
          int ps = (ks * 4 + l4) ^ (r & 7);
          bfr[j] = *(const bf16x8*)(sB + r * 128 + ps * 16);
        }
#pragma unroll
        for (int i = 0; i < IM; ++i)
#pragma unroll
          for (int j = 0; j < JN; ++j)
            acc[i][j] = __builtin_amdgcn_mfma_f32_16x16x32_bf16(af[i], bfr[j], acc[i][j], 0, 0, 0);
      }
      __builtin_amdgcn_s_barrier();
      if (st + 2 < NSTEP) {
        const int kt2 = (st + 2) << 6;
#pragma unroll
        for (int it = 0; it < AI; ++it) gload16(arow[it] + kt2, smem + cur * STRIDE + aoff[it]);
#pragma unroll
        for (int it = 0; it < BI; ++it) gload16(brow[it] + kt2, smem + cur * STRIDE + boff[it]);
        asm volatile("s_waitcnt vmcnt(6)" ::: "memory");
      } else {
        asm volatile("s_waitcnt vmcnt(0)" ::: "memory");
      }
      __builtin_amdgcn_sched_barrier(0);
      __builtin_amdgcn_s_barrier();
      cur ^= 1;
    }

#pragma unroll
    for (int i = 0; i < IM; ++i) {
#pragma unroll
      for (int j = 0; j < JN; ++j) {
        int col = n0 + wc * 16 * JN + j * 16 + l15;
        float bv = biasp[col];
#pragma unroll
        for (int r = 0; r < 4; ++r) {
          int rl = wr * 16 * IM + i * 16 + l4 * 4 + r;
          int grow = m0 + rl;
          if (grow < ne) {
            float val = acc[i][j][r] + bv;
            if (MODE == 2) {
              size_t o = ((size_t)(slot0 + grow)) * NFF + col;
              float c = val * (val * val * 0.044715f + 1.0f) * 0.7978845608f;
              float e = __expf(2.0f * c);
              float gl = 0.5f * val * (1.0f + (e - 1.0f) / (e + 1.0f));
              outb[o] = (bf16)gl;
            } else {
              int tok = perm[slot0 + grow];
              size_t o = (size_t)tok * ND + col;
              outf[o] = val + bf2f(residb[o]);
            }
          }
        }
      }
    }
  }
}

// ---------------------------------------------------------------------------
// Flash attention (r15 drain-staging form) + fused w1/w2 cvt (r17-proven).
// ---------------------------------------------------------------------------
__launch_bounds__(256, 4)
__global__ void attn_kernel(const bf16* __restrict__ qws, const bf16* __restrict__ kws,
                            const bf16* __restrict__ vtws, bf16* __restrict__ attn_out,
                            const float* __restrict__ w1f, const float* __restrict__ w2f,
                            bf16* __restrict__ bw1, bf16* __restrict__ bw2)
{
  const int tid = threadIdx.x, lane = tid & 63, w = tid >> 6;
  const int l4 = lane >> 4, l15 = lane & 15;
  const int bh = blockIdx.y, q0 = blockIdx.x * 64 + w * 16;
  const bf16* Qb = qws + ((size_t)bh * NS + q0) * NHD;
  const bf16* Kb = kws + (size_t)bh * NS * NHD;
  const bf16* Vb = vtws + (size_t)bh * NHD * NS;

  const int fb = blockIdx.y * 32 + blockIdx.x;
  const float* cvsrc;
  bf16* cvdst;
  size_t cbase;
  if (fb < 512) { cvsrc = w1f; cvdst = bw1; cbase = (size_t)fb * 65536; }
  else          { cvsrc = w2f; cvdst = bw2; cbase = (size_t)(fb - 512) * 65536; }

  __shared__ __align__(16) char sK[8192];
  __shared__ __align__(16) char sV[8192];
  __shared__ __align__(16) bf16 sP[4][16][64];

  const int c0 = tid, c1 = 256 + tid;
  const int r0 = c0 >> 3, x0 = ((c0 & 7) ^ (r0 & 7)) * 8;
  const int r1 = c1 >> 3, x1 = ((c1 & 7) ^ (r1 & 7)) * 8;
  const bf16* kst0 = Kb + r0 * NHD + x0;
  const bf16* kst1 = Kb + r1 * NHD + x1;
  const bf16* vst0 = Vb + (size_t)r0 * NS + x0;
  const bf16* vst1 = Vb + (size_t)r1 * NS + x1;
  char* dK0 = sK + tid * 16;        char* dK1 = sK + 4096 + tid * 16;
  char* dV0 = sV + tid * 16;        char* dV1 = sV + 4096 + tid * 16;

  bf16x8 qa[2];
#pragma unroll
  for (int ks = 0; ks < 2; ++ks)
    qa[ks] = *(const bf16x8*)(Qb + (size_t)l15 * NHD + ks * 32 + l4 * 8);

  const f32x4 z4 = {0.f, 0.f, 0.f, 0.f};
  f32x4 o[4];
  float srun[4];
#pragma unroll
  for (int j = 0; j < 4; ++j) o[j] = z4;
#pragma unroll
  for (int r = 0; r < 4; ++r) srun[r] = 0.f;

  for (int t = 0; t < 32; ++t) {
    __syncthreads();
    gload16(kst0 + t * 4096, dK0);
    gload16(kst1 + t * 4096, dK1);
    gload16(vst0 + t * 64, dV0);
    gload16(vst1 + t * 64, dV1);
    __syncthreads();

    const size_t coff = cbase + (size_t)(t * 256 + tid) * 8;
    float4 ca = *(const float4*)(cvsrc + coff);
    float4 cb = *(const float4*)(cvsrc + coff + 4);

    f32x4 s[4];
#pragma unroll
    for (int j = 0; j < 4; ++j) s[j] = z4;
#pragma unroll
    for (int ks = 0; ks < 2; ++ks) {
      bf16x8 kf[4];
#pragma unroll
      for (int j = 0; j < 4; ++j) {
        int r = j * 16 + l15;
        int ps = (ks * 4 + l4) ^ (r & 7);
        kf[j] = *(const bf16x8*)(sK + r * 128 + ps * 16);
      }
#pragma unroll
      for (int j = 0; j < 4; ++j)
        s[j] = __builtin_amdgcn_mfma_f32_16x16x32_bf16(qa[ks], kf[j], s[j], 0, 0, 0);
    }
#pragma unroll
    for (int r = 0; r < 4; ++r) {
      const int row = l4 * 4 + r;
      float ps = 0.f;
#pragma unroll
      for (int j = 0; j < 4; ++j) {
        float p = __expf(s[j][r] * 0.125f);
        int col = j * 16 + l15;
        int slot = (col >> 3) ^ (row & 7);
        sP[w][row][slot * 8 + (col & 7)] = (bf16)p;
        ps += p;
      }
      srun[r] += ps;
    }
#pragma unroll
    for (int ks2 = 0; ks2 < 2; ++ks2) {
      int slot = (ks2 * 4 + l4) ^ (l15 & 7);
      bf16x8 pa = *(const bf16x8*)&sP[w][l15][slot * 8];
      bf16x8 vf[4];
#pragma unroll
      for (int j = 0; j < 4; ++j) {
        int r = j * 16 + l15;
        int ps2 = (ks2 * 4 + l4) ^ (r & 7);
        vf[j] = *(const bf16x8*)(sV + r * 128 + ps2 * 16);
      }
#pragma unroll
      for (int j = 0; j < 4; ++j)
        o[j] = __builtin_amdgcn_mfma_f32_16x16x32_bf16(pa, vf[j], o[j], 0, 0, 0);
    }

    bf16x8 co;
    co[0] = (bf16)ca.x; co[1] = (bf16)ca.y; co[2] = (bf16)ca.z; co[3] = (bf16)ca.w;
    co[4] = (bf16)cb.x; co[5] = (bf16)cb.y; co[6] = (bf16)cb.z; co[7] = (bf16)cb.w;
    *(bf16x8*)(cvdst + coff) = co;
  }

#pragma unroll
  for (int r = 0; r < 4; ++r) {
    float s = srun[r];
    s += __shfl_xor(s, 1); s += __shfl_xor(s, 2);
    s += __shfl_xor(s, 4); s += __shfl_xor(s, 8);
    srun[r] = 1.f / s;
  }
  const int b = bh >> 4, h = bh & 15;
#pragma unroll
  for (int j = 0; j < 4; ++j)
#pragma unroll
    for (int r = 0; r < 4; ++r) {
      int q = q0 + l4 * 4 + r;
      float v = o[j][r] * srun[r];
      attn_out[((size_t)(b * NS + q)) * ND + h * NHD + j * 16 + l15] = (bf16)v;
    }
}

// ---------------------------------------------------------------------------
// Fused LN1 + gate (r17-proven).
// ---------------------------------------------------------------------------
__global__ void ln1_gate_kernel(const float* __restrict__ in, const float* __restrict__ g,
                                const float* __restrict__ b, const float* __restrict__ gw,
                                const float* __restrict__ gb, bf16* __restrict__ u,
                                int* __restrict__ idx, int* __restrict__ counts)
{
  const int t = blockIdx.x, tid = threadIdx.x;
  const int lane = tid & 63, w = tid >> 6;
  const float4 xv = ((const float4*)(in + (size_t)t * ND))[tid];
  __shared__ float red[8];
  __shared__ float sG[4][8];
  float s = xv.x + xv.y + xv.z + xv.w;
  s += __shfl_xor(s, 32); s += __shfl_xor(s, 16); s += __shfl_xor(s, 8);
  s += __shfl_xor(s, 4);  s += __shfl_xor(s, 2);  s += __shfl_xor(s, 1);
  if (lane == 0) red[w] = s;
  __syncthreads();
  const float mean = (red[0] + red[1] + red[2] + red[3]) * (1.f / 1024.f);
  float d0 = xv.x - mean, d1 = xv.y - mean, d2 = xv.z - mean, d3 = xv.w - mean;
  float v = d0 * d0 + d1 * d1 + d2 * d2 + d3 * d3;
  v += __shfl_xor(v, 32); v += __shfl_xor(v, 16); v += __shfl_xor(v, 8);
  v += __shfl_xor(v, 4);  v += __shfl_xor(v, 2);  v += __shfl_xor(v, 1);
  if (lane == 0) red[4 + w] = v;
  __syncthreads();
  const float var = (red[4] + red[5] + red[6] + red[7]) * (1.f / 1024.f);
  const float rstd = rsqrtf(var + 1e-5f);
  const float4 gv = ((const float4*)g)[tid];
  const float4 bv = ((const float4*)b)[tid];
  const float o0 = d0 * rstd * gv.x + bv.x;
  const float o1 = d1 * rstd * gv.y + bv.y;
  const float o2 = d2 * rstd * gv.z + bv.z;
  const float o3 = d3 * rstd * gv.w + bv.w;
  unsigned short u0 = __builtin_bit_cast(unsigned short, (bf16)o0);
  unsigned short u1 = __builtin_bit_cast(unsigned short, (bf16)o1);
  unsigned short u2 = __builtin_bit_cast(unsigned short, (bf16)o2);
  unsigned short u3 = __builtin_bit_cast(unsigned short, (bf16)o3);
  uint2 pk;
  pk.x = (unsigned)u0 | ((unsigned)u1 << 16);
  pk.y = (unsigned)u2 | ((unsigned)u3 << 16);
  ((uint2*)(u + (size_t)t * ND))[tid] = pk;

  float pe[NE];
#pragma unroll
  for (int e = 0; e < NE; ++e) {
    float4 gw4 = ((const float4*)(gw + (size_t)e * ND))[tid];
    pe[e] = o0 * gw4.x + o1 * gw4.y + o2 * gw4.z + o3 * gw4.w;
  }
#pragma unroll
  for (int e = 0; e < NE; ++e) {
    pe[e] += __shfl_xor(pe[e], 32); pe[e] += __shfl_xor(pe[e], 16);
    pe[e] += __shfl_xor(pe[e], 8);  pe[e] += __shfl_xor(pe[e], 4);
    pe[e] += __shfl_xor(pe[e], 2);  pe[e] += __shfl_xor(pe[e], 1);
  }
  if (lane == 0)
#pragma unroll
    for (int e = 0; e < NE; ++e) sG[w][e] = pe[e];
  __syncthreads();
  if (tid == 0) {
    int best = 0;
    float bvv = sG[0][0] + sG[1][0] + sG[2][0] + sG[3][0] + gb[0];
#pragma unroll
    for (int e = 1; e < NE; ++e) {
      float vv = sG[0][e] + sG[1][e] + sG[2][e] + sG[3][e] + gb[e];
      if (vv > bvv) { bvv = vv; best = e; }
    }
    idx[t] = best;
    atomicAdd(&counts[best], 1);
  }
}

// ---------------------------------------------------------------------------
// LayerNorm over D=1024 (LN2), fp32 out.
// ---------------------------------------------------------------------------
__global__ void ln2_kernel(const float* __restrict__ in, const float* __restrict__ g,
                           const float* __restrict__ b, float* __restrict__ outp)
{
  const int t = blockIdx.x, tid = threadIdx.x;
  const float4 xv = ((const float4*)(in + (size_t)t * ND))[tid];
  __shared__ float red[8];
  float s = xv.x + xv.y + xv.z + xv.w;
  s += __shfl_xor(s, 32); s += __shfl_xor(s, 16); s += __shfl_xor(s, 8);
  s += __shfl_xor(s, 4);  s += __shfl_xor(s, 2);  s += __shfl_xor(s, 1);
  if ((tid & 63) == 0) red[tid >> 6] = s;
  __syncthreads();
  const float mean = (red[0] + red[1] + red[2] + red[3]) * (1.f / 1024.f);
  float d0 = xv.x - mean, d1 = xv.y - mean, d2 = xv.z - mean, d3 = xv.w - mean;
  float v = d0 * d0 + d1 * d1 + d2 * d2 + d3 * d3;
  v += __shfl_xor(v, 32); v += __shfl_xor(v, 16); v += __shfl_xor(v, 8);
  v += __shfl_xor(v, 4);  v += __shfl_xor(v, 2);  v += __shfl_xor(v, 1);
  if ((tid & 63) == 0) red[4 + (tid >> 6)] = v;
  __syncthreads();
  const float var = (red[4] + red[5] + red[6] + red[7]) * (1.f / 1024.f);
  const float rstd = rsqrtf(var + 1e-5f);
  const float4 gv = ((const float4*)g)[tid];
  const float4 bv = ((const float4*)b)[tid];
  float4 ov;
  ov.x = d0 * rstd * gv.x + bv.x;
  ov.y = d1 * rstd * gv.y + bv.y;
  ov.z = d2 * rstd * gv.z + bv.z;
  ov.w = d3 * rstd * gv.w + bv.w;
  ((float4*)(outp + (size_t)t * ND))[tid] = ov;
}

// ---------------------------------------------------------------------------
// Merged routing: thread 0 builds offs + tile lists (both BM=64), then all
// 256 threads scatter the 4096 tokens (single-block atomics on cursor).
// Replaces plan_kernel + scatter_kernel (saves one dispatch gap).
// ---------------------------------------------------------------------------
__global__ void route_kernel(const int* __restrict__ counts, const int* __restrict__ idx,
                             int* __restrict__ offs, int* __restrict__ cursor,
                             int* __restrict__ tiles1, int* __restrict__ tiles2,
                             int* __restrict__ perm)
{
  const int tid = threadIdx.x;
  if (tid == 0) {
    int o = 0, n1 = 0, n2 = 0;
    for (int e = 0; e < NE; ++e) {
      offs[e] = o;
      int ne = counts[e];
      int nm = (ne + 63) >> 6;
      for (int m = 0; m < nm; ++m) {
        tiles1[1 + n1++] = (e << 16) | m;
        tiles2[1 + n2++] = (e << 16) | m;
      }
      o += ne;
    }
    offs[NE] = o;
    tiles1[0] = n1;
    tiles2[0] = n2;
  }
  __syncthreads();
  for (int t = tid; t < NT; t += 256) {
    int e = idx[t];
    int pos = offs[e] + atomicAdd(&cursor[e], 1);
    perm[pos] = t;
  }
}

// ---------------------------------------------------------------------------
extern "C" void kernel_launch(void* const* d_in, const int* in_sizes, int n_in,
                              void* d_out, int out_size, void* d_ws, size_t ws_size,
                              hipStream_t stream)
{
  (void)in_sizes; (void)n_in; (void)out_size; (void)ws_size;
  const float* x    = (const float*)d_in[0];
  const float* wqkv = (const float*)d_in[1];
  const float* bqkv = (const float*)d_in[2];
  const float* wo   = (const float*)d_in[3];
  const float* bo   = (const float*)d_in[4];
  const float* ln1g = (const float*)d_in[5];
  const float* ln1b = (const float*)d_in[6];
  const float* ln2g = (const float*)d_in[7];
  const float* ln2b = (const float*)d_in[8];
  const float* gw   = (const float*)d_in[9];
  const float* gb   = (const float*)d_in[10];
  const float* w1   = (const float*)d_in[11];
  const float* b1   = (const float*)d_in[12];
  const float* w2   = (const float*)d_in[13];
  const float* b2   = (const float*)d_in[14];
  float* out = (float*)d_out;

  char* ws = (char*)d_ws;
  bf16*  bx    = (bf16*)(ws + 0);          //  8 MB
  bf16*  bwqkv = (bf16*)(ws + 8388608);    //  6 MB
  bf16*  bwo   = (bf16*)(ws + 14680064);   //  2 MB
  bf16*  bw1   = (bf16*)(ws + 16777216);   // 64 MB
  bf16*  bw2   = (bf16*)(ws + 83886080);   // 64 MB
  bf16*  qws   = (bf16*)(ws + 150994944);  //  8 MB
  bf16*  kws   = (bf16*)(ws + 159383552);  //  8 MB
  bf16*  vtws  = (bf16*)(ws + 167772160);  //  8 MB
  bf16*  aout  = (bf16*)(ws + 176160768);  //  8 MB
  bf16*  hbuf  = (bf16*)(ws + 150994944);  // 32 MB (aliases q/k/vT/aout, dead by then)
  float* x1    = (float*)(ws + 184549376); // 16 MB
  float* x2    = (float*)(ws + 184549376); // aliases x1 (dead after ln1_gate)
  bf16*  u     = (bf16*)(ws + 201326592);  //  8 MB
  int*   meta  = (int*)(ws + 209715200);
  int* idx    = meta;
  int* perm   = meta + 4096;
  int* counts = meta + 8192;
  int* cursor = meta + 8200;
  int* offs   = meta + 8208;
  int* tiles1 = meta + 8224;  // cap 96
  int* tiles2 = meta + 8320;  // cap 96

  // 0. merged fp32->bf16 conversion (x | wqkv | wo) + meta zeroing
  cvt3_kernel<<<4096, 256, 0, stream>>>(x, bx, wqkv, bwqkv, wo, bwo, counts);

  // 1. QKV projection -> q/k/vT
  gemm_bt<0><<<dim3(32, 24), 256, 0, stream>>>(bx, bwqkv, bqkv, nullptr, nullptr,
                                               qws, kws, vtws, NT, 3 * ND, ND);
  // 2. attention + fused w1/w2 cvt
  attn_kernel<<<dim3(32, 32), 256, 0, stream>>>(qws, kws, vtws, aout,
                                                w1, w2, bw1, bw2);
  // 3. out proj + residual -> x1 (fp32)
  gemm_bt<1><<<dim3(32, 8), 256, 0, stream>>>(aout, bwo, bo, x, x1,
                                              nullptr, nullptr, nullptr, NT, ND, ND);
  // 4. LN1 + gate (fused) -> u (bf16), idx, counts
  ln1_gate_kernel<<<4096, 256, 0, stream>>>(x1, ln1g, ln1b, gw, gb, u, idx, counts);
  // 5. routing (merged plan + scatter)
  route_kernel<<<1, 256, 0, stream>>>(counts, idx, offs, cursor, tiles1, tiles2, perm);
  // 6. MoE GEMM1 (counted-vmcnt dbuf, BM=64, 3/CU) -> hbuf = gelu(u@w1^T + b1)
  gemm_moe<2, 64, 3><<<768, 256, 0, stream>>>(u, bw1, b1, nullptr, nullptr, hbuf,
                                              perm, offs, tiles1, NFF / 128, ND);
  // 7. MoE GEMM2 (counted-vmcnt dbuf, BM=64, 3/CU) -> x2[tok] = h@w2^T + b2 + u
  gemm_moe<3, 64, 3><<<576, 256, 0, stream>>>(hbuf, bw2, b2, u, x2, nullptr,
                                              perm, offs, tiles2, ND / 128, NFF);
  // 8. LN2 -> out (fp32)
  ln2_kernel<<<4096, 256, 0, stream>>>(x2, ln2g, ln2b, out);
}

// Round 21
// 412.050 us; speedup vs baseline: 1.0541x; 1.0541x over previous
//
#include <hip/hip_runtime.h>
#include <hip/hip_bf16.h>

typedef __bf16 bf16;
typedef __attribute__((ext_vector_type(8))) __bf16 bf16x8;
typedef __attribute__((ext_vector_type(4))) float f32x4;

#define NB 2
#define NS 2048
#define ND 1024
#define NH 16
#define NHD 64
#define NFF 4096
#define NE 8
#define NT 4096

typedef const void __attribute__((address_space(1)))* gas_p;
typedef void __attribute__((address_space(3)))* las_p;

__device__ __forceinline__ void gload16(const bf16* g, char* l) {
  __builtin_amdgcn_global_load_lds((gas_p)g, (las_p)l, 16, 0, 0);
}

__device__ __forceinline__ float bf2f(bf16 v) { return (float)v; }

// ---------------------------------------------------------------------------
// Merged fp32->bf16 conversion for x (2048 blk), wqkv (1536), wo (512):
// one 4096-block dispatch; block 0 also zeroes the 32 meta ints.
// ---------------------------------------------------------------------------
__global__ void cvt3_kernel(const float* __restrict__ x, bf16* __restrict__ bx,
                            const float* __restrict__ wqkv, bf16* __restrict__ bwqkv,
                            const float* __restrict__ wo, bf16* __restrict__ bwo,
                            int* __restrict__ mz)
{
  const int b = blockIdx.x, tid = threadIdx.x;
  if (b == 0 && tid < 32) mz[tid] = 0;
  const float* src; bf16* dst; size_t off;
  if (b < 2048)      { src = x;    dst = bx;    off = (size_t)b * 2048; }
  else if (b < 3584) { src = wqkv; dst = bwqkv; off = (size_t)(b - 2048) * 2048; }
  else               { src = wo;   dst = bwo;   off = (size_t)(b - 3584) * 2048; }
  const size_t i = off + (size_t)tid * 8;
  float4 a = *(const float4*)(src + i);
  float4 c = *(const float4*)(src + i + 4);
  bf16x8 o;
  o[0] = (bf16)a.x; o[1] = (bf16)a.y; o[2] = (bf16)a.z; o[3] = (bf16)a.w;
  o[4] = (bf16)c.x; o[5] = (bf16)c.y; o[6] = (bf16)c.z; o[7] = (bf16)c.w;
  *(bf16x8*)(dst + i) = o;
}

// ---------------------------------------------------------------------------
// Dense 128x128 B^T GEMM, counted-vmcnt double-buffered (r16-proven):
// MODE 0: QKV proj -> scatter q/k/vT (+fp32 bias)
// MODE 1: out proj -> outf = acc + bias + residf (fp32)
// ---------------------------------------------------------------------------
template<int MODE>
__launch_bounds__(256, 2)
__global__ void gemm_bt(const bf16* __restrict__ A, const bf16* __restrict__ Bw,
                        const float* __restrict__ bias, const float* __restrict__ residf,
                        float* __restrict__ outf,
                        bf16* __restrict__ qws, bf16* __restrict__ kws, bf16* __restrict__ vtws,
                        int M, int N, int K)
{
  constexpr int STRIDE = 32768;
  __shared__ __align__(16) char smem[2 * STRIDE];
  const int tid = threadIdx.x;
  const int lane = tid & 63, w = tid >> 6;
  const int wr = w >> 1, wc = w & 1;
  const int l4 = lane >> 4, l15 = lane & 15;
  const int m0 = blockIdx.x * 128, n0 = blockIdx.y * 128;

  const bf16* arow[4];
  const bf16* brow[4];
  int aoff[4], boff[4];
#pragma unroll
  for (int it = 0; it < 4; ++it) {
    int chunk = it * 256 + tid;
    int row = chunk >> 3, p = chunk & 7;
    int xoff = (p ^ (row & 7)) * 8;
    aoff[it] = chunk * 16;
    boff[it] = 16384 + chunk * 16;
    arow[it] = A + (size_t)(m0 + row) * K + xoff;
    brow[it] = Bw + (size_t)(n0 + row) * K + xoff;
  }

  f32x4 acc[4][4];
  const f32x4 z4 = {0.f, 0.f, 0.f, 0.f};
#pragma unroll
  for (int i = 0; i < 4; ++i)
#pragma unroll
    for (int j = 0; j < 4; ++j) acc[i][j] = z4;

  const int NSTEP = K >> 6;
#pragma unroll
  for (int it = 0; it < 4; ++it) { gload16(arow[it], smem + aoff[it]);
                                   gload16(brow[it], smem + boff[it]); }
#pragma unroll
  for (int it = 0; it < 4; ++it) { gload16(arow[it] + 64, smem + STRIDE + aoff[it]);
                                   gload16(brow[it] + 64, smem + STRIDE + boff[it]); }
  asm volatile("s_waitcnt vmcnt(8)" ::: "memory");
  __builtin_amdgcn_sched_barrier(0);
  __builtin_amdgcn_s_barrier();

  int cur = 0;
  for (int st = 0; st < NSTEP; ++st) {
    const char* sA = smem + cur * STRIDE;
    const char* sB = sA + 16384;
#pragma unroll
    for (int ks = 0; ks < 2; ++ks) {
      bf16x8 af[4], bfr[4];
#pragma unroll
      for (int i = 0; i < 4; ++i) {
        int r = wr * 64 + i * 16 + l15;
        int ps = (ks * 4 + l4) ^ (r & 7);
        af[i] = *(const bf16x8*)(sA + r * 128 + ps * 16);
      }
#pragma unroll
      for (int j = 0; j < 4; ++j) {
        int r = wc * 64 + j * 16 + l15;
        int ps = (ks * 4 + l4) ^ (r & 7);
        bfr[j] = *(const bf16x8*)(sB + r * 128 + ps * 16);
      }
#pragma unroll
      for (int i = 0; i < 4; ++i)
#pragma unroll
        for (int j = 0; j < 4; ++j)
          acc[i][j] = __builtin_amdgcn_mfma_f32_16x16x32_bf16(af[i], bfr[j], acc[i][j], 0, 0, 0);
    }
    __builtin_amdgcn_s_barrier();
    if (st + 2 < NSTEP) {
      const int kt2 = (st + 2) << 6;
#pragma unroll
      for (int it = 0; it < 4; ++it) { gload16(arow[it] + kt2, smem + cur * STRIDE + aoff[it]);
                                       gload16(brow[it] + kt2, smem + cur * STRIDE + boff[it]); }
      asm volatile("s_waitcnt vmcnt(8)" ::: "memory");
    } else {
      asm volatile("s_waitcnt vmcnt(0)" ::: "memory");
    }
    __builtin_amdgcn_sched_barrier(0);
    __builtin_amdgcn_s_barrier();
    cur ^= 1;
  }

#pragma unroll
  for (int i = 0; i < 4; ++i) {
#pragma unroll
    for (int j = 0; j < 4; ++j) {
      int col = n0 + wc * 64 + j * 16 + l15;
      float bv = bias[col];
#pragma unroll
      for (int r = 0; r < 4; ++r) {
        int rl = wr * 64 + i * 16 + l4 * 4 + r;
        int grow = m0 + rl;
        float val = acc[i][j][r] + bv;
        if (MODE == 0) {
          int b = grow >> 11, s = grow & 2047;
          int which = col >> 10, d = col & 1023;
          int h = d >> 6, hd = d & 63;
          int bh = b * NH + h;
          if (which == 0)      qws[((size_t)(bh * NS + s)) * NHD + hd] = (bf16)val;
          else if (which == 1) kws[((size_t)(bh * NS + s)) * NHD + hd] = (bf16)val;
          else                 vtws[((size_t)(bh * NHD + hd)) * NS + s] = (bf16)val;
        } else {
          size_t o = (size_t)grow * ND + col;
          outf[o] = val + residf[o];
        }
      }
    }
  }
}

// ---------------------------------------------------------------------------
// Persistent MoE GEMM, counted-vmcnt double-buffered (r14/r17-proven, BM=64).
// MODE 2: GEMM1  outb[slot] = gelu(A[perm]@w1^T + b1)   (tanh GELU)
// MODE 3: GEMM2  outf[tok]  = A[slot]@w2^T + b2 + residb[tok]
// ---------------------------------------------------------------------------
template<int MODE, int BM, int MINW>
__launch_bounds__(256, MINW)
__global__ void gemm_moe(const bf16* __restrict__ A, const bf16* __restrict__ Bw,
                         const float* __restrict__ bias, const bf16* __restrict__ residb,
                         float* __restrict__ outf, bf16* __restrict__ outb,
                         const int* __restrict__ perm, const int* __restrict__ offs,
                         const int* __restrict__ tiles, int NTILN, int K)
{
  constexpr int BN = 128;
  constexpr int AI = BM / 32;
  constexpr int BI = 4;
  constexpr int STRIDE = (BM + BN) * 128;
  constexpr int WM = 2, WN = 2;
  constexpr int IM = BM / (16 * WM);
  constexpr int JN = BN / (16 * WN);
  __shared__ __align__(16) char smem[2 * STRIDE];
  const int tid = threadIdx.x;
  const int lane = tid & 63, w = tid >> 6;
  const int wr = w >> 1, wc = w & 1;
  const int l4 = lane >> 4, l15 = lane & 15;

  const int nmt = tiles[0];
  const int ntile = nmt * NTILN;
  const int q8 = ntile >> 3, r8 = ntile & 7;
  const int NSTEP = K >> 6;

  for (int u = blockIdx.x; u < ntile; u += gridDim.x) {
    const int xcd = u & 7, pos = u >> 3;
    const int t = (xcd < r8 ? xcd * (q8 + 1) : r8 * (q8 + 1) + (xcd - r8) * q8) + pos;

    const int mi = t % nmt, nj = t / nmt;
    const int pk = tiles[1 + mi];
    const int z = pk >> 16;
    const int m0 = (pk & 0xffff) * BM;
    const int n0 = nj * BN;
    const int slot0 = offs[z];
    const int ne = offs[z + 1] - slot0;
    const bf16* Bp = Bw + (size_t)z * ((MODE == 2) ? (NFF * ND) : (ND * NFF));
    const float* biasp = bias + z * ((MODE == 2) ? NFF : ND);

    const bf16* arow[AI];
    const bf16* brow[BI];
    int aoff[AI], boff[BI];
#pragma unroll
    for (int it = 0; it < AI; ++it) {
      int chunk = it * 256 + tid;
      int row = chunk >> 3, p = chunk & 7;
      int xoff = (p ^ (row & 7)) * 8;
      aoff[it] = chunk * 16;
      if (MODE == 2) {
        int tok = perm[slot0 + min(m0 + row, ne - 1)];
        arow[it] = A + (size_t)tok * K + xoff;
      } else {
        int r2 = min(m0 + row, ne - 1);
        arow[it] = A + (size_t)(slot0 + r2) * K + xoff;
      }
    }
#pragma unroll
    for (int it = 0; it < BI; ++it) {
      int chunk = it * 256 + tid;
      int row = chunk >> 3, p = chunk & 7;
      int xoff = (p ^ (row & 7)) * 8;
      boff[it] = BM * 128 + chunk * 16;
      brow[it] = Bp + (size_t)(n0 + row) * K + xoff;
    }

    f32x4 acc[IM][JN];
    const f32x4 z4 = {0.f, 0.f, 0.f, 0.f};
#pragma unroll
    for (int i = 0; i < IM; ++i)
#pragma unroll
      for (int j = 0; j < JN; ++j) acc[i][j] = z4;

#pragma unroll
    for (int it = 0; it < AI; ++it) gload16(arow[it], smem + aoff[it]);
#pragma unroll
    for (int it = 0; it < BI; ++it) gload16(brow[it], smem + boff[it]);
#pragma unroll
    for (int it = 0; it < AI; ++it) gload16(arow[it] + 64, smem + STRIDE + aoff[it]);
#pragma unroll
    for (int it = 0; it < BI; ++it) gload16(brow[it] + 64, smem + STRIDE + boff[it]);
    asm volatile("s_waitcnt vmcnt(6)" ::: "memory");
    __builtin_amdgcn_sched_barrier(0);
    __builtin_amdgcn_s_barrier();

    int cur = 0;
    for (int st = 0; st < NSTEP; ++st) {
      const char* sA = smem + cur * STRIDE;
      const char* sB = sA + BM * 128;
#pragma unroll
      for (int ks = 0; ks < 2; ++ks) {
        bf16x8 af[IM], bfr[JN];
#pragma unroll
        for (int i = 0; i < IM; ++i) {
          int r = wr * 16 * IM + i * 16 + l15;
          int ps = (ks * 4 + l4) ^ (r & 7);
          af[i] = *(const bf16x8*)(sA + r * 128 + ps * 16);
        }
#pragma unroll
        for (int j = 0; j < JN; ++j) {
          int r = wc * 16 * JN + j * 16 + l15;
          int ps = (ks * 4 + l4) ^ (r & 7);
          bfr[j] = *(const bf16x8*)(sB + r * 128 + ps * 16);
        }
#pragma unroll
        for (int i = 0; i < IM; ++i)
#pragma unroll
          for (int j = 0; j < JN; ++j)
            acc[i][j] = __builtin_amdgcn_mfma_f32_16x16x32_bf16(af[i], bfr[j], acc[i][j], 0, 0, 0);
      }
      __builtin_amdgcn_s_barrier();
      if (st + 2 < NSTEP) {
        const int kt2 = (st + 2) << 6;
#pragma unroll
        for (int it = 0; it < AI; ++it) gload16(arow[it] + kt2, smem + cur * STRIDE + aoff[it]);
#pragma unroll
        for (int it = 0; it < BI; ++it) gload16(brow[it] + kt2, smem + cur * STRIDE + boff[it]);
        asm volatile("s_waitcnt vmcnt(6)" ::: "memory");
      } else {
        asm volatile("s_waitcnt vmcnt(0)" ::: "memory");
      }
      __builtin_amdgcn_sched_barrier(0);
      __builtin_amdgcn_s_barrier();
      cur ^= 1;
    }

#pragma unroll
    for (int i = 0; i < IM; ++i) {
#pragma unroll
      for (int j = 0; j < JN; ++j) {
        int col = n0 + wc * 16 * JN + j * 16 + l15;
        float bv = biasp[col];
#pragma unroll
        for (int r = 0; r < 4; ++r) {
          int rl = wr * 16 * IM + i * 16 + l4 * 4 + r;
          int grow = m0 + rl;
          if (grow < ne) {
            float val = acc[i][j][r] + bv;
            if (MODE == 2) {
              size_t o = ((size_t)(slot0 + grow)) * NFF + col;
              float c = val * (val * val * 0.044715f + 1.0f) * 0.7978845608f;
              float e = __expf(2.0f * c);
              float gl = 0.5f * val * (1.0f + (e - 1.0f) / (e + 1.0f));
              outb[o] = (bf16)gl;
            } else {
              int tok = perm[slot0 + grow];
              size_t o = (size_t)tok * ND + col;
              outf[o] = val + bf2f(residb[o]);
            }
          }
        }
      }
    }
  }
}

// ---------------------------------------------------------------------------
// Flash attention (r15 drain-staging form) + fused w1/w2 cvt (r17-proven).
// ---------------------------------------------------------------------------
__launch_bounds__(256, 4)
__global__ void attn_kernel(const bf16* __restrict__ qws, const bf16* __restrict__ kws,
                            const bf16* __restrict__ vtws, bf16* __restrict__ attn_out,
                            const float* __restrict__ w1f, const float* __restrict__ w2f,
                            bf16* __restrict__ bw1, bf16* __restrict__ bw2)
{
  const int tid = threadIdx.x, lane = tid & 63, w = tid >> 6;
  const int l4 = lane >> 4, l15 = lane & 15;
  const int bh = blockIdx.y, q0 = blockIdx.x * 64 + w * 16;
  const bf16* Qb = qws + ((size_t)bh * NS + q0) * NHD;
  const bf16* Kb = kws + (size_t)bh * NS * NHD;
  const bf16* Vb = vtws + (size_t)bh * NHD * NS;

  const int fb = blockIdx.y * 32 + blockIdx.x;
  const float* cvsrc;
  bf16* cvdst;
  size_t cbase;
  if (fb < 512) { cvsrc = w1f; cvdst = bw1; cbase = (size_t)fb * 65536; }
  else          { cvsrc = w2f; cvdst = bw2; cbase = (size_t)(fb - 512) * 65536; }

  __shared__ __align__(16) char sK[8192];
  __shared__ __align__(16) char sV[8192];
  __shared__ __align__(16) bf16 sP[4][16][64];

  const int c0 = tid, c1 = 256 + tid;
  const int r0 = c0 >> 3, x0 = ((c0 & 7) ^ (r0 & 7)) * 8;
  const int r1 = c1 >> 3, x1 = ((c1 & 7) ^ (r1 & 7)) * 8;
  const bf16* kst0 = Kb + r0 * NHD + x0;
  const bf16* kst1 = Kb + r1 * NHD + x1;
  const bf16* vst0 = Vb + (size_t)r0 * NS + x0;
  const bf16* vst1 = Vb + (size_t)r1 * NS + x1;
  char* dK0 = sK + tid * 16;        char* dK1 = sK + 4096 + tid * 16;
  char* dV0 = sV + tid * 16;        char* dV1 = sV + 4096 + tid * 16;

  bf16x8 qa[2];
#pragma unroll
  for (int ks = 0; ks < 2; ++ks)
    qa[ks] = *(const bf16x8*)(Qb + (size_t)l15 * NHD + ks * 32 + l4 * 8);

  const f32x4 z4 = {0.f, 0.f, 0.f, 0.f};
  f32x4 o[4];
  float srun[4];
#pragma unroll
  for (int j = 0; j < 4; ++j) o[j] = z4;
#pragma unroll
  for (int r = 0; r < 4; ++r) srun[r] = 0.f;

  for (int t = 0; t < 32; ++t) {
    __syncthreads();
    gload16(kst0 + t * 4096, dK0);
    gload16(kst1 + t * 4096, dK1);
    gload16(vst0 + t * 64, dV0);
    gload16(vst1 + t * 64, dV1);
    __syncthreads();

    const size_t coff = cbase + (size_t)(t * 256 + tid) * 8;
    float4 ca = *(const float4*)(cvsrc + coff);
    float4 cb = *(const float4*)(cvsrc + coff + 4);

    f32x4 s[4];
#pragma unroll
    for (int j = 0; j < 4; ++j) s[j] = z4;
#pragma unroll
    for (int ks = 0; ks < 2; ++ks) {
      bf16x8 kf[4];
#pragma unroll
      for (int j = 0; j < 4; ++j) {
        int r = j * 16 + l15;
        int ps = (ks * 4 + l4) ^ (r & 7);
        kf[j] = *(const bf16x8*)(sK + r * 128 + ps * 16);
      }
#pragma unroll
      for (int j = 0; j < 4; ++j)
        s[j] = __builtin_amdgcn_mfma_f32_16x16x32_bf16(qa[ks], kf[j], s[j], 0, 0, 0);
    }
#pragma unroll
    for (int r = 0; r < 4; ++r) {
      const int row = l4 * 4 + r;
      float ps = 0.f;
#pragma unroll
      for (int j = 0; j < 4; ++j) {
        float p = __expf(s[j][r] * 0.125f);
        int col = j * 16 + l15;
        int slot = (col >> 3) ^ (row & 7);
        sP[w][row][slot * 8 + (col & 7)] = (bf16)p;
        ps += p;
      }
      srun[r] += ps;
    }
#pragma unroll
    for (int ks2 = 0; ks2 < 2; ++ks2) {
      int slot = (ks2 * 4 + l4) ^ (l15 & 7);
      bf16x8 pa = *(const bf16x8*)&sP[w][l15][slot * 8];
      bf16x8 vf[4];
#pragma unroll
      for (int j = 0; j < 4; ++j) {
        int r = j * 16 + l15;
        int ps2 = (ks2 * 4 + l4) ^ (r & 7);
        vf[j] = *(const bf16x8*)(sV + r * 128 + ps2 * 16);
      }
#pragma unroll
      for (int j = 0; j < 4; ++j)
        o[j] = __builtin_amdgcn_mfma_f32_16x16x32_bf16(pa, vf[j], o[j], 0, 0, 0);
    }

    bf16x8 co;
    co[0] = (bf16)ca.x; co[1] = (bf16)ca.y; co[2] = (bf16)ca.z; co[3] = (bf16)ca.w;
    co[4] = (bf16)cb.x; co[5] = (bf16)cb.y; co[6] = (bf16)cb.z; co[7] = (bf16)cb.w;
    *(bf16x8*)(cvdst + coff) = co;
  }

#pragma unroll
  for (int r = 0; r < 4; ++r) {
    float s = srun[r];
    s += __shfl_xor(s, 1); s += __shfl_xor(s, 2);
    s += __shfl_xor(s, 4); s += __shfl_xor(s, 8);
    srun[r] = 1.f / s;
  }
  const int b = bh >> 4, h = bh & 15;
#pragma unroll
  for (int j = 0; j < 4; ++j)
#pragma unroll
    for (int r = 0; r < 4; ++r) {
      int q = q0 + l4 * 4 + r;
      float v = o[j][r] * srun[r];
      attn_out[((size_t)(b * NS + q)) * ND + h * NHD + j * 16 + l15] = (bf16)v;
    }
}

// ---------------------------------------------------------------------------
// Fused LN1 + gate (r17-proven).
// ---------------------------------------------------------------------------
__global__ void ln1_gate_kernel(const float* __restrict__ in, const float* __restrict__ g,
                                const float* __restrict__ b, const float* __restrict__ gw,
                                const float* __restrict__ gb, bf16* __restrict__ u,
                                int* __restrict__ idx, int* __restrict__ counts)
{
  const int t = blockIdx.x, tid = threadIdx.x;
  const int lane = tid & 63, w = tid >> 6;
  const float4 xv = ((const float4*)(in + (size_t)t * ND))[tid];
  __shared__ float red[8];
  __shared__ float sG[4][8];
  float s = xv.x + xv.y + xv.z + xv.w;
  s += __shfl_xor(s, 32); s += __shfl_xor(s, 16); s += __shfl_xor(s, 8);
  s += __shfl_xor(s, 4);  s += __shfl_xor(s, 2);  s += __shfl_xor(s, 1);
  if (lane == 0) red[w] = s;
  __syncthreads();
  const float mean = (red[0] + red[1] + red[2] + red[3]) * (1.f / 1024.f);
  float d0 = xv.x - mean, d1 = xv.y - mean, d2 = xv.z - mean, d3 = xv.w - mean;
  float v = d0 * d0 + d1 * d1 + d2 * d2 + d3 * d3;
  v += __shfl_xor(v, 32); v += __shfl_xor(v, 16); v += __shfl_xor(v, 8);
  v += __shfl_xor(v, 4);  v += __shfl_xor(v, 2);  v += __shfl_xor(v, 1);
  if (lane == 0) red[4 + w] = v;
  __syncthreads();
  const float var = (red[4] + red[5] + red[6] + red[7]) * (1.f / 1024.f);
  const float rstd = rsqrtf(var + 1e-5f);
  const float4 gv = ((const float4*)g)[tid];
  const float4 bv = ((const float4*)b)[tid];
  const float o0 = d0 * rstd * gv.x + bv.x;
  const float o1 = d1 * rstd * gv.y + bv.y;
  const float o2 = d2 * rstd * gv.z + bv.z;
  const float o3 = d3 * rstd * gv.w + bv.w;
  unsigned short u0 = __builtin_bit_cast(unsigned short, (bf16)o0);
  unsigned short u1 = __builtin_bit_cast(unsigned short, (bf16)o1);
  unsigned short u2 = __builtin_bit_cast(unsigned short, (bf16)o2);
  unsigned short u3 = __builtin_bit_cast(unsigned short, (bf16)o3);
  uint2 pk;
  pk.x = (unsigned)u0 | ((unsigned)u1 << 16);
  pk.y = (unsigned)u2 | ((unsigned)u3 << 16);
  ((uint2*)(u + (size_t)t * ND))[tid] = pk;

  float pe[NE];
#pragma unroll
  for (int e = 0; e < NE; ++e) {
    float4 gw4 = ((const float4*)(gw + (size_t)e * ND))[tid];
    pe[e] = o0 * gw4.x + o1 * gw4.y + o2 * gw4.z + o3 * gw4.w;
  }
#pragma unroll
  for (int e = 0; e < NE; ++e) {
    pe[e] += __shfl_xor(pe[e], 32); pe[e] += __shfl_xor(pe[e], 16);
    pe[e] += __shfl_xor(pe[e], 8);  pe[e] += __shfl_xor(pe[e], 4);
    pe[e] += __shfl_xor(pe[e], 2);  pe[e] += __shfl_xor(pe[e], 1);
  }
  if (lane == 0)
#pragma unroll
    for (int e = 0; e < NE; ++e) sG[w][e] = pe[e];
  __syncthreads();
  if (tid == 0) {
    int best = 0;
    float bvv = sG[0][0] + sG[1][0] + sG[2][0] + sG[3][0] + gb[0];
#pragma unroll
    for (int e = 1; e < NE; ++e) {
      float vv = sG[0][e] + sG[1][e] + sG[2][e] + sG[3][e] + gb[e];
      if (vv > bvv) { bvv = vv; best = e; }
    }
    idx[t] = best;
    atomicAdd(&counts[best], 1);
  }
}

// ---------------------------------------------------------------------------
// LayerNorm over D=1024 (LN2), fp32 out.
// ---------------------------------------------------------------------------
__global__ void ln2_kernel(const float* __restrict__ in, const float* __restrict__ g,
                           const float* __restrict__ b, float* __restrict__ outp)
{
  const int t = blockIdx.x, tid = threadIdx.x;
  const float4 xv = ((const float4*)(in + (size_t)t * ND))[tid];
  __shared__ float red[8];
  float s = xv.x + xv.y + xv.z + xv.w;
  s += __shfl_xor(s, 32); s += __shfl_xor(s, 16); s += __shfl_xor(s, 8);
  s += __shfl_xor(s, 4);  s += __shfl_xor(s, 2);  s += __shfl_xor(s, 1);
  if ((tid & 63) == 0) red[tid >> 6] = s;
  __syncthreads();
  const float mean = (red[0] + red[1] + red[2] + red[3]) * (1.f / 1024.f);
  float d0 = xv.x - mean, d1 = xv.y - mean, d2 = xv.z - mean, d3 = xv.w - mean;
  float v = d0 * d0 + d1 * d1 + d2 * d2 + d3 * d3;
  v += __shfl_xor(v, 32); v += __shfl_xor(v, 16); v += __shfl_xor(v, 8);
  v += __shfl_xor(v, 4);  v += __shfl_xor(v, 2);  v += __shfl_xor(v, 1);
  if ((tid & 63) == 0) red[4 + (tid >> 6)] = v;
  __syncthreads();
  const float var = (red[4] + red[5] + red[6] + red[7]) * (1.f / 1024.f);
  const float rstd = rsqrtf(var + 1e-5f);
  const float4 gv = ((const float4*)g)[tid];
  const float4 bv = ((const float4*)b)[tid];
  float4 ov;
  ov.x = d0 * rstd * gv.x + bv.x;
  ov.y = d1 * rstd * gv.y + bv.y;
  ov.z = d2 * rstd * gv.z + bv.z;
  ov.w = d3 * rstd * gv.w + bv.w;
  ((float4*)(outp + (size_t)t * ND))[tid] = ov;
}

// counts -> offs, plus compact tile lists (both BM=64)
__global__ void plan_kernel(const int* __restrict__ counts, int* __restrict__ offs,
                            int* __restrict__ tiles1, int* __restrict__ tiles2)
{
  if (threadIdx.x != 0) return;
  int o = 0, n1 = 0, n2 = 0;
  for (int e = 0; e < NE; ++e) {
    offs[e] = o;
    int ne = counts[e];
    int nm = (ne + 63) >> 6;
    for (int m = 0; m < nm; ++m) {
      tiles1[1 + n1++] = (e << 16) | m;
      tiles2[1 + n2++] = (e << 16) | m;
    }
    o += ne;
  }
  offs[NE] = o;
  tiles1[0] = n1;
  tiles2[0] = n2;
}

__global__ void scatter_kernel(const int* __restrict__ idx, const int* __restrict__ offs,
                               int* __restrict__ cursor, int* __restrict__ perm)
{
  int t = blockIdx.x * 256 + threadIdx.x;
  int e = idx[t];
  int pos = offs[e] + atomicAdd(&cursor[e], 1);
  perm[pos] = t;
}

// ---------------------------------------------------------------------------
extern "C" void kernel_launch(void* const* d_in, const int* in_sizes, int n_in,
                              void* d_out, int out_size, void* d_ws, size_t ws_size,
                              hipStream_t stream)
{
  (void)in_sizes; (void)n_in; (void)out_size; (void)ws_size;
  const float* x    = (const float*)d_in[0];
  const float* wqkv = (const float*)d_in[1];
  const float* bqkv = (const float*)d_in[2];
  const float* wo   = (const float*)d_in[3];
  const float* bo   = (const float*)d_in[4];
  const float* ln1g = (const float*)d_in[5];
  const float* ln1b = (const float*)d_in[6];
  const float* ln2g = (const float*)d_in[7];
  const float* ln2b = (const float*)d_in[8];
  const float* gw   = (const float*)d_in[9];
  const float* gb   = (const float*)d_in[10];
  const float* w1   = (const float*)d_in[11];
  const float* b1   = (const float*)d_in[12];
  const float* w2   = (const float*)d_in[13];
  const float* b2   = (const float*)d_in[14];
  float* out = (float*)d_out;

  char* ws = (char*)d_ws;
  bf16*  bx    = (bf16*)(ws + 0);          //  8 MB
  bf16*  bwqkv = (bf16*)(ws + 8388608);    //  6 MB
  bf16*  bwo   = (bf16*)(ws + 14680064);   //  2 MB
  bf16*  bw1   = (bf16*)(ws + 16777216);   // 64 MB
  bf16*  bw2   = (bf16*)(ws + 83886080);   // 64 MB
  bf16*  qws   = (bf16*)(ws + 150994944);  //  8 MB
  bf16*  kws   = (bf16*)(ws + 159383552);  //  8 MB
  bf16*  vtws  = (bf16*)(ws + 167772160);  //  8 MB
  bf16*  aout  = (bf16*)(ws + 176160768);  //  8 MB
  bf16*  hbuf  = (bf16*)(ws + 150994944);  // 32 MB (aliases q/k/vT/aout, dead by then)
  float* x1    = (float*)(ws + 184549376); // 16 MB
  float* x2    = (float*)(ws + 184549376); // aliases x1 (dead after ln1_gate)
  bf16*  u     = (bf16*)(ws + 201326592);  //  8 MB
  int*   meta  = (int*)(ws + 209715200);
  int* idx    = meta;
  int* perm   = meta + 4096;
  int* counts = meta + 8192;
  int* cursor = meta + 8200;
  int* offs   = meta + 8208;
  int* tiles1 = meta + 8224;  // cap 96
  int* tiles2 = meta + 8320;  // cap 96

  // 0. merged fp32->bf16 conversion (x | wqkv | wo) + meta zeroing
  cvt3_kernel<<<4096, 256, 0, stream>>>(x, bx, wqkv, bwqkv, wo, bwo, counts);

  // 1. QKV projection -> q/k/vT
  gemm_bt<0><<<dim3(32, 24), 256, 0, stream>>>(bx, bwqkv, bqkv, nullptr, nullptr,
                                               qws, kws, vtws, NT, 3 * ND, ND);
  // 2. attention + fused w1/w2 cvt
  attn_kernel<<<dim3(32, 32), 256, 0, stream>>>(qws, kws, vtws, aout,
                                                w1, w2, bw1, bw2);
  // 3. out proj + residual -> x1 (fp32)
  gemm_bt<1><<<dim3(32, 8), 256, 0, stream>>>(aout, bwo, bo, x, x1,
                                              nullptr, nullptr, nullptr, NT, ND, ND);
  // 4. LN1 + gate (fused) -> u (bf16), idx, counts
  ln1_gate_kernel<<<4096, 256, 0, stream>>>(x1, ln1g, ln1b, gw, gb, u, idx, counts);
  // 5. routing plan + scatter (separate dispatches; merged version regressed r20)
  plan_kernel<<<1, 64, 0, stream>>>(counts, offs, tiles1, tiles2);
  scatter_kernel<<<16, 256, 0, stream>>>(idx, offs, cursor, perm);
  // 6. MoE GEMM1 (counted-vmcnt dbuf, BM=64, 3/CU) -> hbuf = gelu(u@w1^T + b1)
  gemm_moe<2, 64, 3><<<768, 256, 0, stream>>>(u, bw1, b1, nullptr, nullptr, hbuf,
                                              perm, offs, tiles1, NFF / 128, ND);
  // 7. MoE GEMM2 (counted-vmcnt dbuf, BM=64, 3/CU) -> x2[tok] = h@w2^T + b2 + u
  gemm_moe<3, 64, 3><<<576, 256, 0, stream>>>(hbuf, bw2, b2, u, x2, nullptr,
                                              perm, offs, tiles2, ND / 128, NFF);
  // 8. LN2 -> out (fp32)
  ln2_kernel<<<4096, 256, 0, stream>>>(x2, ln2g, ln2b, out);
}